// Round 10
// baseline (553.302 us; speedup 1.0000x reference)
//
#include <hip/hip_runtime.h>
#include <hip/hip_bf16.h>
#include <cstdint>

// Shapes: B=512, S=196, I=2048, Q=1024, H=512
// ques_attn == ques_feat exactly (softmax over singleton axis). Only img_attn computed:
//   cc[b][h]  = sum_q qf[b][q]*w2g[q][h] + b2g[h] + b2x[h]
//   score[r]  = sum_h tanh( sum_k X[r][k]*w2x[k][h] + cc[b(r)][h] ) * w2h[h]   (r = b*196+s)
//   a = softmax_s(score);  img_attn[b][f] = sum_s a[b][s] * X[b][s][f]
//
// r10: K-step 128 (16 barriers), 4 x 32KB f32 LDS buffers, DMA distance 3 issued at
// step TOP; B-fragments TRIPLE-buffered so every vmcnt wait lands >=3 phases after
// the op it transitively forces (in-order retire => no hidden HBM/L2 stalls).
// While the f32 tile is in LDS, store its bf16 image to ws -> k_wsum reads half.

typedef __attribute__((ext_vector_type(8))) short bf16x8;
typedef __attribute__((ext_vector_type(4))) float f32x4;

typedef __attribute__((address_space(1))) const unsigned int as1_uint;
typedef __attribute__((address_space(3))) unsigned int as3_uint;

__device__ inline unsigned short f2bf(float f) {
    union { float f; unsigned u; } v; v.f = f;
    unsigned u = v.u;
    u += 0x7FFFu + ((u >> 16) & 1u);
    return (unsigned short)(u >> 16);
}

__device__ inline unsigned pk2(float lo, float hi) {
    __hip_bfloat162 h = __float22bfloat162_rn(make_float2(lo, hi));
    return *reinterpret_cast<unsigned*>(&h);
}

__device__ inline unsigned pkq(unsigned a, unsigned b) {
    union { unsigned u; float f; } x, y; x.u = a; y.u = b;
    return pk2(x.f, y.f);
}

// 8 f32 (two uint4) -> bf16x8
__device__ inline bf16x8 cvt8(uint4 lo, uint4 hi) {
    union { unsigned u[4]; bf16x8 v; } r;
    r.u[0] = pkq(lo.x, lo.y); r.u[1] = pkq(lo.z, lo.w);
    r.u[2] = pkq(hi.x, hi.y); r.u[3] = pkq(hi.z, hi.w);
    return r.v;
}

__device__ inline float bfhi(unsigned u) {
    union { unsigned u; float f; } v; v.u = u & 0xFFFF0000u; return v.f;
}
__device__ inline float bflo(unsigned u) {
    union { unsigned u; float f; } v; v.u = u << 16; return v.f;
}

// ---------------- out0 = ques_feat (exact copy) ----------------
__global__ void k_copy(const float* __restrict__ src, float* __restrict__ dst) {
    int i = blockIdx.x * blockDim.x + threadIdx.x;
    reinterpret_cast<float4*>(dst)[i] = reinterpret_cast<const float4*>(src)[i];
}

// ---------------- WTf: fragment-major packed bf16 of w2x^T ----------------
__global__ void k_pack_w(const float* __restrict__ w, unsigned short* __restrict__ wtf) {
    int kblk = blockIdx.x >> 5;
    int nblk = blockIdx.x & 31;
    int t = threadIdx.x;          // 128: (kc8, col)
    int kc8 = t >> 4, col = t & 15;
    const float* src = w + (size_t)(kblk * 64 + kc8 * 8) * 512 + nblk * 16 + col;
    unsigned short* dst = wtf + (size_t)(kblk * 32 + nblk) * 1024 + kc8 * 128 + col * 8;
    unsigned short tmp[8];
    #pragma unroll
    for (int j = 0; j < 8; ++j) tmp[j] = f2bf(src[(size_t)j * 512]);
    *reinterpret_cast<uint4*>(dst) = *reinterpret_cast<const uint4*>(tmp);
}

// ---------------- cc[b][h] = qf[b]·w2g[:,h] + b2g[h] + b2x[h] ----------------
__global__ void k_cconst(const float* __restrict__ qf, const float* __restrict__ w2g,
                         const float* __restrict__ b2g, const float* __restrict__ b2x,
                         float* __restrict__ cc) {
    __shared__ float qls[2][1024];
    int b0 = blockIdx.x * 2;
    int t = threadIdx.x;
    #pragma unroll
    for (int j = 0; j < 2; ++j) {
        int idx = j * 256 + t;
        int bb = idx >> 8, c4 = idx & 255;
        float4 v = reinterpret_cast<const float4*>(qf + (size_t)(b0 + bb) * 1024)[c4];
        qls[bb][c4 * 4 + 0] = v.x; qls[bb][c4 * 4 + 1] = v.y;
        qls[bb][c4 * 4 + 2] = v.z; qls[bb][c4 * 4 + 3] = v.w;
    }
    __syncthreads();
    float a00 = 0.f, a01 = 0.f, a10 = 0.f, a11 = 0.f;
    #pragma unroll 8
    for (int q = 0; q < 1024; ++q) {
        float w0 = w2g[q * 512 + t];
        float w1 = w2g[q * 512 + 256 + t];
        float q0 = qls[0][q], q1 = qls[1][q];
        a00 += q0 * w0; a01 += q0 * w1;
        a10 += q1 * w0; a11 += q1 * w1;
    }
    float c0 = b2g[t] + b2x[t];
    float c1 = b2g[t + 256] + b2x[t + 256];
    cc[(size_t)b0 * 512 + t] = a00 + c0;
    cc[(size_t)b0 * 512 + t + 256] = a01 + c1;
    cc[(size_t)(b0 + 1) * 512 + t] = a10 + c0;
    cc[(size_t)(b0 + 1) * 512 + t + 256] = a11 + c1;
}

// ---------------- scores: fused GEMM + tanh + dot(w2h), K-step 128 ----------------
// grid 1568 M-tiles of 64 rows; block 512 = 8 waves, wave owns 64 cols (acc 64).
// LDS: 4 x 32KB f32 A-buffers. Granule (16B) at pos (row*32 + pc) holds source
// col-group gcol = pc ^ (row&31) (involution; conflict-free DMA + frag reads).
// DOX: also emit bf16 image of each tile to xbf (linear /2 of the LDS layout).
#define NSTEP 16

template<int DOX>
__global__ __launch_bounds__(512, 2) void k_scores_t(
    const float* __restrict__ X, const unsigned short* __restrict__ WTf,
    const float* __restrict__ cc, const float* __restrict__ w2h,
    float* __restrict__ scores, unsigned short* __restrict__ xbf)
{
    __shared__ __align__(16) char Ab[4][32768];
    __shared__ float slds[64];

    int tid = threadIdx.x;
    int wave = tid >> 6, lane = tid & 63;
    int l15 = lane & 15, l4 = lane >> 4;
    int r0 = blockIdx.x * 64;

    // DMA staging: thread t covers granules t + 512j (j=0..3): rows srow+16j, pc = t&31
    int srow = tid >> 5;          // 0..15
    int spc = tid & 31;
    int g0 = (spc ^ srow) << 4;           // byte offset of source col-group, rows 0-15 / 32-47
    int g1 = (spc ^ (srow + 16)) << 4;    // rows 16-31 / 48-63
    const char* xs0 = reinterpret_cast<const char*>(X + (size_t)(r0 + srow) * 2048) + g0;
    const char* xs1 = reinterpret_cast<const char*>(X + (size_t)(r0 + srow + 16) * 2048) + g1;
    const char* xs2 = reinterpret_cast<const char*>(X + (size_t)(r0 + srow + 32) * 2048) + g0;
    const char* xs3 = reinterpret_cast<const char*>(X + (size_t)(r0 + srow + 48) * 2048) + g1;
    char* ldsw = &Ab[0][0] + wave * 1024;   // + j*8192 + bufofs; lane*16 implicit

    // B fragment base
    const unsigned short* wb0 = WTf + (size_t)wave * 4096 + l4 * 128 + l15 * 8;

    // A fragment voffsets: pc = q_h ^ (kh*8) ^ ((m&1)*16), byte = m*8192 + l15*512 + pc*16
    const char* abase = &Ab[0][0];
    int q0v = ((l4 * 2 + 0) ^ l15) << 4;
    int q1v = ((l4 * 2 + 1) ^ l15) << 4;
    int voff0 = l15 * 512 + q0v;
    int voff1 = l15 * 512 + q1v;

    char* xd = reinterpret_cast<char*>(xbf) + (size_t)blockIdx.x * 262144 + tid * 32;

    if (tid < 64) slds[tid] = 0.0f;

    f32x4 acc[4][4];
    #pragma unroll
    for (int m = 0; m < 4; ++m)
        #pragma unroll
        for (int n = 0; n < 4; ++n) acc[m][n] = (f32x4){0.f, 0.f, 0.f, 0.f};

    bf16x8 brA[4], brB[4], brC[4];

    #define GLL(src, dst) __builtin_amdgcn_global_load_lds( \
        (as1_uint*)(src), (as3_uint*)(dst), 16, 0, 2)

    #define GLOAD4(bufofs, step) do { \
        GLL(xs0 + (size_t)(step) * 512, ldsw + (bufofs)); \
        GLL(xs1 + (size_t)(step) * 512, ldsw + (bufofs) + 8192); \
        GLL(xs2 + (size_t)(step) * 512, ldsw + (bufofs) + 16384); \
        GLL(xs3 + (size_t)(step) * 512, ldsw + (bufofs) + 24576); } while (0)

    #define BLOAD(dst, t, kh) do { \
        const unsigned short* bp = wb0 + (size_t)(2 * (t) + ((kh) >> 1)) * 32768 + ((kh) & 1) * 512; \
        dst[0] = *reinterpret_cast<const bf16x8*>(bp); \
        dst[1] = *reinterpret_cast<const bf16x8*>(bp + 1024); \
        dst[2] = *reinterpret_cast<const bf16x8*>(bp + 2048); \
        dst[3] = *reinterpret_cast<const bf16x8*>(bp + 3072); } while (0)

    #define MF(br, bufofs, kh) do { \
        __builtin_amdgcn_s_setprio(1); \
        _Pragma("unroll") \
        for (int m = 0; m < 4; ++m) { \
            int cst = ((kh) * 128) ^ ((m & 1) * 256); \
            uint4 lo = *reinterpret_cast<const uint4*>(abase + (bufofs) + m * 8192 + (voff0 ^ cst)); \
            uint4 hi = *reinterpret_cast<const uint4*>(abase + (bufofs) + m * 8192 + (voff1 ^ cst)); \
            bf16x8 af = cvt8(lo, hi); \
            _Pragma("unroll") \
            for (int n = 0; n < 4; ++n) \
                acc[m][n] = __builtin_amdgcn_mfma_f32_16x16x32_bf16(af, br[n], acc[m][n], 0, 0, 0); \
        } \
        __builtin_amdgcn_s_setprio(0); } while (0)

    #define STORE_TILE(bufofs, t) do { if (DOX) { \
        const uint4* sp = reinterpret_cast<const uint4*>(abase + (bufofs) + tid * 64); \
        uint4 s0 = sp[0], s1 = sp[1], s2 = sp[2], s3 = sp[3]; \
        uint4 o0, o1; \
        o0.x = pkq(s0.x, s0.y); o0.y = pkq(s0.z, s0.w); \
        o0.z = pkq(s1.x, s1.y); o0.w = pkq(s1.z, s1.w); \
        o1.x = pkq(s2.x, s2.y); o1.y = pkq(s2.z, s2.w); \
        o1.z = pkq(s3.x, s3.y); o1.w = pkq(s3.z, s3.w); \
        *reinterpret_cast<uint4*>(xd + (size_t)(t) * 16384) = o0; \
        *reinterpret_cast<uint4*>(xd + (size_t)(t) * 16384 + 16) = o1; } } while (0)

    // One K-step: DMA(t+3) at TOP (before any B-load of the step), then 4 phases,
    // each: MFMA on a set loaded exactly 3 phases earlier, then reload that set.
    #define STEP(T, SA, SB, SC, LAST) do { \
        const int bo_ = ((T) & 3) * 32768; \
        if ((T) + 3 < NSTEP) GLOAD4((((T) + 3) & 3) * 32768, (T) + 3); \
        MF(SA, bo_, 0); BLOAD(SA, (T), 3); \
        MF(SB, bo_, 1); if (!(LAST)) BLOAD(SB, (T) + 1, 0); \
        MF(SC, bo_, 2); if (!(LAST)) BLOAD(SC, (T) + 1, 1); \
        MF(SA, bo_, 3); if (!(LAST)) BLOAD(SA, (T) + 1, 2); \
        STORE_TILE(bo_, T); \
        __builtin_amdgcn_sched_barrier(0); \
        __builtin_amdgcn_s_barrier(); } while (0)

    // prologue: DMA steps 0..2; B phases 0..2; retire DMA(0) (24 issued -> vmcnt 20)
    GLOAD4(0, 0);
    GLOAD4(32768, 1);
    GLOAD4(65536, 2);
    BLOAD(brA, 0, 0);
    BLOAD(brB, 0, 1);
    BLOAD(brC, 0, 2);
    asm volatile("s_waitcnt vmcnt(20)" ::: "memory");
    __builtin_amdgcn_s_barrier();

    #pragma unroll 1
    for (int T = 0; T < 15; T += 3) {
        STEP(T,     brA, brB, brC, 0);
        STEP(T + 1, brB, brC, brA, 0);
        STEP(T + 2, brC, brA, brB, 0);
    }
    STEP(15, brA, brB, brC, 1);

    // fence: keep epilogue constant loads out of the K-loop
    asm volatile("" ::: "memory");

    // epilogue: score[row] = sum_h tanh(feat + cc[b(row)][h]) * w2h[h]
    int b0 = r0 / 196;
    int sbreak = (b0 + 1) * 196 - r0;
    int b1 = b0 + 1; if (b1 > 511) b1 = 511;
    float cch0[4], cch1[4], whv[4];
    #pragma unroll
    for (int n = 0; n < 4; ++n) {
        int h = wave * 64 + n * 16 + l15;
        cch0[n] = cc[(size_t)b0 * 512 + h];
        cch1[n] = cc[(size_t)b1 * 512 + h];
        whv[n] = w2h[h];
    }
    #pragma unroll
    for (int m = 0; m < 4; ++m) {
        #pragma unroll
        for (int i = 0; i < 4; ++i) {
            int row = m * 16 + l4 * 4 + i;
            float p = 0.0f;
            #pragma unroll
            for (int n = 0; n < 4; ++n) {
                float x = acc[m][n][i] + ((row < sbreak) ? cch0[n] : cch1[n]);
                float th = 1.0f - 2.0f / (__expf(2.0f * x) + 1.0f);
                p += th * whv[n];
            }
            p += __shfl_xor(p, 1);
            p += __shfl_xor(p, 2);
            p += __shfl_xor(p, 4);
            p += __shfl_xor(p, 8);
            if (l15 == 0) atomicAdd(&slds[row], p);
        }
    }
    __syncthreads();
    if (tid < 64) scores[(size_t)r0 + tid] = slds[tid];
}

// ---------------- softmax over s (196) per b ----------------
__global__ void k_softmax(float* sc) {
    int b = blockIdx.x, t = threadIdx.x;
    __shared__ float red[8];
    float v = (t < 196) ? sc[(size_t)b * 196 + t] : -3.0e38f;
    float m = v;
    for (int o = 32; o > 0; o >>= 1) m = fmaxf(m, __shfl_xor(m, o));
    if ((t & 63) == 0) red[t >> 6] = m;
    __syncthreads();
    m = fmaxf(fmaxf(red[0], red[1]), fmaxf(red[2], red[3]));
    float e = (t < 196) ? __expf(v - m) : 0.0f;
    float s = e;
    for (int o = 32; o > 0; o >>= 1) s += __shfl_xor(s, o);
    if ((t & 63) == 0) red[4 + (t >> 6)] = s;
    __syncthreads();
    float tot = red[4] + red[5] + red[6] + red[7];
    if (t < 196) sc[(size_t)b * 196 + t] = e / tot;
}

// ---------------- wsum from the bf16 tile image ----------------
// Image layout: tile (64 rows) * 256KB; step (128 cols) * 16KB; granule (4 bf16, 8B)
// at pos row*32 + (gcolin ^ (row&31)).
__global__ __launch_bounds__(256) void k_wsum_bf(const unsigned short* __restrict__ Xbf,
                                                 const float* __restrict__ a,
                                                 float* __restrict__ out1) {
    __shared__ float als[196];
    int b = blockIdx.x >> 1;
    int half = blockIdx.x & 1;
    int t = threadIdx.x;
    if (t < 196) als[t] = a[(size_t)b * 196 + t];
    __syncthreads();
    int f = half * 1024 + t * 4;
    int cg = f >> 2;                 // global col-granule 0..511
    int step = cg >> 5;
    int gcolin = cg & 31;
    const char* xb = reinterpret_cast<const char*>(Xbf);
    float a0 = 0.f, a1 = 0.f, a2 = 0.f, a3 = 0.f;
    int r = b * 196;
    #pragma unroll 4
    for (int s = 0; s < 196; ++s, ++r) {
        int tile = r >> 6, row = r & 63;
        size_t byte = (size_t)tile * 262144 + (size_t)step * 16384
                      + (size_t)(row * 32 + (gcolin ^ (row & 31))) * 8;
        uint2 v = *reinterpret_cast<const uint2*>(xb + byte);
        float w = als[s];
        a0 += w * bflo(v.x); a1 += w * bfhi(v.x);
        a2 += w * bflo(v.y); a3 += w * bfhi(v.y);
    }
    float4 o = {a0, a1, a2, a3};
    *reinterpret_cast<float4*>(out1 + (size_t)b * 2048 + f) = o;
}

// ---------------- f32 wsum fallback ----------------
__global__ void k_wsum(const float* __restrict__ X, const float* __restrict__ a,
                       float* __restrict__ out1) {
    __shared__ float als[196];
    int b = blockIdx.x >> 1;
    int fh = (blockIdx.x & 1) * 1024;
    int t = threadIdx.x;
    if (t < 196) als[t] = a[(size_t)b * 196 + t];
    __syncthreads();
    int f = fh + t * 4;
    const float* Xb = X + (size_t)b * 196 * 2048 + f;
    float4 acc = {0.f, 0.f, 0.f, 0.f};
    #pragma unroll 4
    for (int s = 0; s < 196; ++s) {
        float4 x = *reinterpret_cast<const float4*>(Xb + (size_t)s * 2048);
        float w = als[s];
        acc.x += w * x.x; acc.y += w * x.y; acc.z += w * x.z; acc.w += w * x.w;
    }
    *reinterpret_cast<float4*>(out1 + (size_t)b * 2048 + f) = acc;
}

extern "C" void kernel_launch(void* const* d_in, const int* in_sizes, int n_in,
                              void* d_out, int out_size, void* d_ws, size_t ws_size,
                              hipStream_t stream) {
    const float* qf  = (const float*)d_in[0];
    const float* X   = (const float*)d_in[1];
    const float* w2x = (const float*)d_in[6];
    const float* b2x = (const float*)d_in[7];
    const float* w2g = (const float*)d_in[8];
    const float* b2g = (const float*)d_in[9];
    const float* w2h = (const float*)d_in[10];

    float* out0 = (float*)d_out;                 // ques_attn = ques_feat (512x1024)
    float* out1 = out0 + 512 * 1024;             // img_attn (512x2048)

    // ws layout: [0,2MB) WTf; [2MB,3MB) cc; [3MB,4MB) scores flat [100352]; [4MB,..) Xbf
    unsigned short* WTf = (unsigned short*)d_ws;
    float* cc = (float*)((char*)d_ws + (size_t)(2u << 20));
    float* sc = (float*)((char*)d_ws + (size_t)(3u << 20));
    unsigned short* xbf = (unsigned short*)((char*)d_ws + (size_t)(4u << 20));
    const size_t XBF_BYTES = (size_t)1568 * 262144;   // 411 MB
    int big = (ws_size >= (size_t)(4u << 20) + XBF_BYTES) ? 1 : 0;

    k_copy<<<512, 256, 0, stream>>>(qf, out0);
    k_pack_w<<<1024, 128, 0, stream>>>(w2x, WTf);
    k_cconst<<<256, 256, 0, stream>>>(qf, w2g, b2g, b2x, cc);
    if (big) {
        k_scores_t<1><<<1568, 512, 0, stream>>>(X, WTf, cc, w2h, sc, xbf);
        k_softmax<<<512, 256, 0, stream>>>(sc);
        k_wsum_bf<<<1024, 256, 0, stream>>>(xbf, sc, out1);
    } else {
        k_scores_t<0><<<1568, 512, 0, stream>>>(X, WTf, cc, w2h, sc, xbf);
        k_softmax<<<512, 256, 0, stream>>>(sc);
        k_wsum<<<1024, 256, 0, stream>>>(X, sc, out1);
    }
}

// Round 11
// 550.114 us; speedup vs baseline: 1.0058x; 1.0058x over previous
//
#include <hip/hip_runtime.h>
#include <hip/hip_bf16.h>
#include <cstdint>

// Shapes: B=512, S=196, I=2048, Q=1024, H=512
// ques_attn == ques_feat exactly (softmax over singleton axis). Only img_attn computed:
//   cc[b][h]  = sum_q qf[b][q]*w2g[q][h] + b2g[h] + b2x[h]
//   score[r]  = sum_h tanh( sum_k X[r][k]*w2x[k][h] + cc[b(r)][h] ) * w2h[h]   (r = b*196+s)
//   a = softmax_s(score);  img_attn[b][f] = sum_s a[b][s] * X[b][s][f]
//
// r11 = r9 (best: f32-X direct staging, 4x16KB buffers, 2 blocks/CU, distance-3
// DMA, NT) + bf16 tile-image store inside k_scores (16B/thread/step, reads the
// LDS buffer being consumed this step; barrier orders it before that buffer's
// next DMA) -> k_wsum reads 411MB bf16 instead of 822MB f32.

typedef __attribute__((ext_vector_type(8))) short bf16x8;
typedef __attribute__((ext_vector_type(4))) float f32x4;

typedef __attribute__((address_space(1))) const unsigned int as1_uint;
typedef __attribute__((address_space(3))) unsigned int as3_uint;

__device__ inline unsigned short f2bf(float f) {
    union { float f; unsigned u; } v; v.f = f;
    unsigned u = v.u;
    u += 0x7FFFu + ((u >> 16) & 1u);
    return (unsigned short)(u >> 16);
}

__device__ inline unsigned pk2(float lo, float hi) {
    __hip_bfloat162 h = __float22bfloat162_rn(make_float2(lo, hi));
    return *reinterpret_cast<unsigned*>(&h);
}

__device__ inline unsigned pkq(unsigned a, unsigned b) {
    union { unsigned u; float f; } x, y; x.u = a; y.u = b;
    return pk2(x.f, y.f);
}

// 8 f32 (two uint4) -> bf16x8 via v_cvt_pk_bf16_f32
__device__ inline bf16x8 cvt8(uint4 lo, uint4 hi) {
    union { unsigned u[4]; bf16x8 v; } r;
    r.u[0] = pkq(lo.x, lo.y); r.u[1] = pkq(lo.z, lo.w);
    r.u[2] = pkq(hi.x, hi.y); r.u[3] = pkq(hi.z, hi.w);
    return r.v;
}

__device__ inline float bfhi(unsigned u) {
    union { unsigned u; float f; } v; v.u = u & 0xFFFF0000u; return v.f;
}
__device__ inline float bflo(unsigned u) {
    union { unsigned u; float f; } v; v.u = u << 16; return v.f;
}

// ---------------- out0 = ques_feat (exact copy) ----------------
__global__ void k_copy(const float* __restrict__ src, float* __restrict__ dst) {
    int i = blockIdx.x * blockDim.x + threadIdx.x;
    reinterpret_cast<float4*>(dst)[i] = reinterpret_cast<const float4*>(src)[i];
}

// ---------------- WTf: fragment-major packed bf16 of w2x^T ----------------
// Tile (kblk, nblk) = 64 k x 16 cols: [kc8 0..7][col 0..15][j 0..7];
// a wave's B-fragment read (16 cols x 32 k) is one contiguous 1 KB access.
__global__ void k_pack_w(const float* __restrict__ w, unsigned short* __restrict__ wtf) {
    int kblk = blockIdx.x >> 5;
    int nblk = blockIdx.x & 31;
    int t = threadIdx.x;          // 128: (kc8, col)
    int kc8 = t >> 4, col = t & 15;
    const float* src = w + (size_t)(kblk * 64 + kc8 * 8) * 512 + nblk * 16 + col;
    unsigned short* dst = wtf + (size_t)(kblk * 32 + nblk) * 1024 + kc8 * 128 + col * 8;
    unsigned short tmp[8];
    #pragma unroll
    for (int j = 0; j < 8; ++j) tmp[j] = f2bf(src[(size_t)j * 512]);
    *reinterpret_cast<uint4*>(dst) = *reinterpret_cast<const uint4*>(tmp);
}

// ---------------- cc[b][h] = qf[b]·w2g[:,h] + b2g[h] + b2x[h] ----------------
__global__ void k_cconst(const float* __restrict__ qf, const float* __restrict__ w2g,
                         const float* __restrict__ b2g, const float* __restrict__ b2x,
                         float* __restrict__ cc) {
    __shared__ float qls[2][1024];
    int b0 = blockIdx.x * 2;
    int t = threadIdx.x;
    #pragma unroll
    for (int j = 0; j < 2; ++j) {
        int idx = j * 256 + t;
        int bb = idx >> 8, c4 = idx & 255;
        float4 v = reinterpret_cast<const float4*>(qf + (size_t)(b0 + bb) * 1024)[c4];
        qls[bb][c4 * 4 + 0] = v.x; qls[bb][c4 * 4 + 1] = v.y;
        qls[bb][c4 * 4 + 2] = v.z; qls[bb][c4 * 4 + 3] = v.w;
    }
    __syncthreads();
    float a00 = 0.f, a01 = 0.f, a10 = 0.f, a11 = 0.f;
    #pragma unroll 8
    for (int q = 0; q < 1024; ++q) {
        float w0 = w2g[q * 512 + t];
        float w1 = w2g[q * 512 + 256 + t];
        float q0 = qls[0][q], q1 = qls[1][q];
        a00 += q0 * w0; a01 += q0 * w1;
        a10 += q1 * w0; a11 += q1 * w1;
    }
    float c0 = b2g[t] + b2x[t];
    float c1 = b2g[t + 256] + b2x[t + 256];
    cc[(size_t)b0 * 512 + t] = a00 + c0;
    cc[(size_t)b0 * 512 + t + 256] = a01 + c1;
    cc[(size_t)(b0 + 1) * 512 + t] = a10 + c0;
    cc[(size_t)(b0 + 1) * 512 + t + 256] = a11 + c1;
}

// ---------------- scores: fused GEMM + tanh + dot(w2h), f32-X direct ----------------
// grid 1568 M-tiles of 64 rows; block 512 = 8 waves, wave owns 64 cols (acc 64 AGPR).
// K-step 64. A staged as f32: per step 64 rows x 64 f32 = 16KB = 1024 granules(16B).
// Granule at LDS pos p (=row*16+pc): content f32 col-group gcol = pc ^ (row&15)
// (involution) -> DMA dest linear (wave-uniform+lane*16), per-lane swizzled SOURCE.
// Frag read: two ds_read_b128 at pc=(kh*8+l4*2+h)^l15 -> conflict-free.
// DOX=1: additionally store the bf16 image of each consumed tile (granule pos p
// -> image byte p*8) so k_wsum_bf reads half the bytes.
#define NSTEP 32

template<int DOX>
__global__ __launch_bounds__(512, 4) void k_scores_t(
    const float* __restrict__ X, const unsigned short* __restrict__ WTf,
    const float* __restrict__ cc, const float* __restrict__ w2h,
    float* __restrict__ scores, unsigned short* __restrict__ xbf)
{
    __shared__ __align__(16) char Ab[4][16384];   // 4 x 16KB f32 A-buffers
    __shared__ float slds[64];

    int tid = threadIdx.x;
    int wave = tid >> 6, lane = tid & 63;
    int l15 = lane & 15, l4 = lane >> 4;
    int r0 = blockIdx.x * 64;

    // staging: thread t stages granules t (rows 0..31) and t+512 (rows 32..63)
    int srow = tid >> 4, spc = tid & 15;
    const char* xsrc = reinterpret_cast<const char*>(X + (size_t)(r0 + srow) * 2048)
                       + ((spc ^ (srow & 15)) << 4);
    const char* xsrc2 = xsrc + (size_t)32 * 8192;   // row+32: same (row&15) -> same swizzle
    char* ldsw = &Ab[0][0] + wave * 1024;           // + bufofs (+8192 for 2nd granule)

    // B fragment base; (n,kh) offsets are immediates off bp
    const unsigned short* wb0 = WTf + (size_t)wave * 4096 + l4 * 128 + l15 * 8;

    // A fragment byte voffsets: l15*256 + (( kh*8 + l4*2 + h ) ^ l15)*16
    const char* abase = &Ab[0][0];
    int off00 = l15 * 256 + (((l4 * 2 + 0) ^ l15) << 4);
    int off01 = l15 * 256 + (((l4 * 2 + 1) ^ l15) << 4);
    int off10 = l15 * 256 + (((8 + l4 * 2 + 0) ^ l15) << 4);
    int off11 = l15 * 256 + (((8 + l4 * 2 + 1) ^ l15) << 4);

    // bf16 image destination (256KB per tile: 32 steps x 8KB)
    char* xd = reinterpret_cast<char*>(xbf) + (size_t)blockIdx.x * 262144 + tid * 16;

    if (tid < 64) slds[tid] = 0.0f;

    f32x4 acc[4][4];
    #pragma unroll
    for (int m = 0; m < 4; ++m)
        #pragma unroll
        for (int n = 0; n < 4; ++n) acc[m][n] = (f32x4){0.f, 0.f, 0.f, 0.f};

    bf16x8 brA[4], brB[4];

    // aux=2 (NT): X is a pure stream; don't evict the L2-hot WTf panel
    #define GLOAD2(bufofs, step) do { \
        __builtin_amdgcn_global_load_lds((as1_uint*)(xsrc + (step) * 256), \
            (as3_uint*)(ldsw + (bufofs)), 16, 0, 2); \
        __builtin_amdgcn_global_load_lds((as1_uint*)(xsrc2 + (step) * 256), \
            (as3_uint*)(ldsw + (bufofs) + 8192), 16, 0, 2); } while (0)

    #define BLOAD(dst, t, kh) do { \
        const unsigned short* bp = wb0 + (size_t)(t) * 32768 + (kh) * 512; \
        dst[0] = *reinterpret_cast<const bf16x8*>(bp); \
        dst[1] = *reinterpret_cast<const bf16x8*>(bp + 1024); \
        dst[2] = *reinterpret_cast<const bf16x8*>(bp + 2048); \
        dst[3] = *reinterpret_cast<const bf16x8*>(bp + 3072); } while (0)

    #define MF(br, bufofs, offL, offH) do { \
        __builtin_amdgcn_s_setprio(1); \
        _Pragma("unroll") \
        for (int m = 0; m < 4; ++m) { \
            uint4 lo = *reinterpret_cast<const uint4*>(abase + (bufofs) + m * 4096 + (offL)); \
            uint4 hi = *reinterpret_cast<const uint4*>(abase + (bufofs) + m * 4096 + (offH)); \
            bf16x8 af = cvt8(lo, hi); \
            _Pragma("unroll") \
            for (int n = 0; n < 4; ++n) \
                acc[m][n] = __builtin_amdgcn_mfma_f32_16x16x32_bf16(af, br[n], acc[m][n], 0, 0, 0); \
        } \
        __builtin_amdgcn_s_setprio(0); } while (0)

    // Store bf16 image of the tile consumed this step. Reads LDS granules 2*tid,
    // 2*tid+1 of buffer bufofs (valid all step; its next DMA overwrite is issued
    // only after this step's barrier). One 16B store, fully coalesced.
    #define STORE_TILE(bufofs, t) do { if (DOX) { \
        const uint4* sp = reinterpret_cast<const uint4*>(abase + (bufofs) + tid * 32); \
        uint4 s0 = sp[0], s1 = sp[1]; \
        uint4 o; \
        o.x = pkq(s0.x, s0.y); o.y = pkq(s0.z, s0.w); \
        o.z = pkq(s1.x, s1.y); o.w = pkq(s1.z, s1.w); \
        *reinterpret_cast<uint4*>(xd + (size_t)(t) * 8192) = o; } } while (0)

    #define SBAR __builtin_amdgcn_sched_barrier(0)

    // prologue: fill DMA pipeline 3 deep; retire DMA(0), keep DMA(1,2)+B(0) in flight
    GLOAD2(0, 0);
    GLOAD2(16384, 1);
    GLOAD2(32768, 2);
    BLOAD(brA, 0, 0);
    asm volatile("s_waitcnt vmcnt(8)" ::: "memory");
    __builtin_amdgcn_s_barrier();

    // steady state: wait-for-brB(t-1) at step t-1 transitively retires DMA(t)
    // (issued step t-3, older) before barrier(t-1) -> buf t safe at step t.
    #pragma unroll 1
    for (int t = 0; t < NSTEP; ++t) {
        int bufofs = (t & 3) * 16384;
        BLOAD(brB, t, 1);
        MF(brA, bufofs, off00, off01);
        if (t + 1 < NSTEP) BLOAD(brA, t + 1, 0);
        MF(brB, bufofs, off10, off11);
        STORE_TILE(bufofs, t);
        SBAR;
        if (t + 3 < NSTEP) GLOAD2(((t + 3) & 3) * 16384, t + 3);
        SBAR;
        __builtin_amdgcn_s_barrier();
    }

    // fence: keep epilogue constant loads out of the K-loop
    asm volatile("" ::: "memory");

    // epilogue: score[row] = sum_h tanh(feat + cc[b(row)][h]) * w2h[h]
    int b0 = r0 / 196;
    int sbreak = (b0 + 1) * 196 - r0;
    int b1 = b0 + 1; if (b1 > 511) b1 = 511;
    float cch0[4], cch1[4], whv[4];
    #pragma unroll
    for (int n = 0; n < 4; ++n) {
        int h = wave * 64 + n * 16 + l15;
        cch0[n] = cc[(size_t)b0 * 512 + h];
        cch1[n] = cc[(size_t)b1 * 512 + h];
        whv[n] = w2h[h];
    }
    #pragma unroll
    for (int m = 0; m < 4; ++m) {
        #pragma unroll
        for (int i = 0; i < 4; ++i) {
            int row = m * 16 + l4 * 4 + i;
            float p = 0.0f;
            #pragma unroll
            for (int n = 0; n < 4; ++n) {
                float x = acc[m][n][i] + ((row < sbreak) ? cch0[n] : cch1[n]);
                float th = 1.0f - 2.0f / (__expf(2.0f * x) + 1.0f);
                p += th * whv[n];
            }
            p += __shfl_xor(p, 1);
            p += __shfl_xor(p, 2);
            p += __shfl_xor(p, 4);
            p += __shfl_xor(p, 8);
            if (l15 == 0) atomicAdd(&slds[row], p);
        }
    }
    __syncthreads();
    if (tid < 64) scores[(size_t)r0 + tid] = slds[tid];
}

// ---------------- softmax over s (196) per b ----------------
__global__ void k_softmax(float* sc) {
    int b = blockIdx.x, t = threadIdx.x;
    __shared__ float red[8];
    float v = (t < 196) ? sc[(size_t)b * 196 + t] : -3.0e38f;
    float m = v;
    for (int o = 32; o > 0; o >>= 1) m = fmaxf(m, __shfl_xor(m, o));
    if ((t & 63) == 0) red[t >> 6] = m;
    __syncthreads();
    m = fmaxf(fmaxf(red[0], red[1]), fmaxf(red[2], red[3]));
    float e = (t < 196) ? __expf(v - m) : 0.0f;
    float s = e;
    for (int o = 32; o > 0; o >>= 1) s += __shfl_xor(s, o);
    if ((t & 63) == 0) red[4 + (t >> 6)] = s;
    __syncthreads();
    float tot = red[4] + red[5] + red[6] + red[7];
    if (t < 196) sc[(size_t)b * 196 + t] = e / tot;
}

// ---------------- wsum from the bf16 tile image ----------------
// Image: tile(64 rows)=256KB; step(64 cols)=8KB; granule pos p=row*16+pc at byte
// p*8 holds cols gcol*4..+3 where gcol = pc ^ (row&15).
__global__ __launch_bounds__(256) void k_wsum_bf(const unsigned short* __restrict__ Xbf,
                                                 const float* __restrict__ a,
                                                 float* __restrict__ out1) {
    __shared__ float als[196];
    int b = blockIdx.x >> 1;
    int half = blockIdx.x & 1;
    int t = threadIdx.x;
    if (t < 196) als[t] = a[(size_t)b * 196 + t];
    __syncthreads();
    int f = half * 1024 + t * 4;
    int step = f >> 6;
    int gcol = (f & 63) >> 2;        // granule column 0..15
    const char* xb = reinterpret_cast<const char*>(Xbf);
    float a0 = 0.f, a1 = 0.f, a2 = 0.f, a3 = 0.f;
    int r = b * 196;
    #pragma unroll 4
    for (int s = 0; s < 196; ++s, ++r) {
        int tile = r >> 6, row = r & 63;
        int pc = gcol ^ (row & 15);
        size_t byte = (size_t)tile * 262144 + (size_t)step * 8192
                      + (size_t)(row * 16 + pc) * 8;
        uint2 v = *reinterpret_cast<const uint2*>(xb + byte);
        float w = als[s];
        a0 += w * bflo(v.x); a1 += w * bfhi(v.x);
        a2 += w * bflo(v.y); a3 += w * bfhi(v.y);
    }
    float4 o = {a0, a1, a2, a3};
    *reinterpret_cast<float4*>(out1 + (size_t)b * 2048 + f) = o;
}

// ---------------- f32 wsum fallback ----------------
__global__ void k_wsum(const float* __restrict__ X, const float* __restrict__ a,
                       float* __restrict__ out1) {
    __shared__ float als[196];
    int b = blockIdx.x >> 1;
    int fh = (blockIdx.x & 1) * 1024;
    int t = threadIdx.x;
    if (t < 196) als[t] = a[(size_t)b * 196 + t];
    __syncthreads();
    int f = fh + t * 4;
    const float* Xb = X + (size_t)b * 196 * 2048 + f;
    float4 acc = {0.f, 0.f, 0.f, 0.f};
    #pragma unroll 4
    for (int s = 0; s < 196; ++s) {
        float4 x = *reinterpret_cast<const float4*>(Xb + (size_t)s * 2048);
        float w = als[s];
        acc.x += w * x.x; acc.y += w * x.y; acc.z += w * x.z; acc.w += w * x.w;
    }
    *reinterpret_cast<float4*>(out1 + (size_t)b * 2048 + f) = acc;
}

extern "C" void kernel_launch(void* const* d_in, const int* in_sizes, int n_in,
                              void* d_out, int out_size, void* d_ws, size_t ws_size,
                              hipStream_t stream) {
    const float* qf  = (const float*)d_in[0];
    const float* X   = (const float*)d_in[1];
    const float* w2x = (const float*)d_in[6];
    const float* b2x = (const float*)d_in[7];
    const float* w2g = (const float*)d_in[8];
    const float* b2g = (const float*)d_in[9];
    const float* w2h = (const float*)d_in[10];

    float* out0 = (float*)d_out;                 // ques_attn = ques_feat (512x1024)
    float* out1 = out0 + 512 * 1024;             // img_attn (512x2048)

    // ws layout: [0,2MB) WTf; [2MB,3MB) cc; [3MB,4MB) scores flat [100352]; [4MB,..) Xbf
    unsigned short* WTf = (unsigned short*)d_ws;
    float* cc = (float*)((char*)d_ws + (size_t)(2u << 20));
    float* sc = (float*)((char*)d_ws + (size_t)(3u << 20));
    unsigned short* xbf = (unsigned short*)((char*)d_ws + (size_t)(4u << 20));
    const size_t XBF_BYTES = (size_t)1568 * 262144;   // 411 MB
    int big = (ws_size >= (size_t)(4u << 20) + XBF_BYTES) ? 1 : 0;

    k_copy<<<512, 256, 0, stream>>>(qf, out0);
    k_pack_w<<<1024, 128, 0, stream>>>(w2x, WTf);
    k_cconst<<<256, 256, 0, stream>>>(qf, w2g, b2g, b2x, cc);
    if (big) {
        k_scores_t<1><<<1568, 512, 0, stream>>>(X, WTf, cc, w2h, sc, xbf);
        k_softmax<<<512, 256, 0, stream>>>(sc);
        k_wsum_bf<<<1024, 256, 0, stream>>>(xbf, sc, out1);
    } else {
        k_scores_t<0><<<1568, 512, 0, stream>>>(X, WTf, cc, w2h, sc, xbf);
        k_softmax<<<512, 256, 0, stream>>>(sc);
        k_wsum<<<1024, 256, 0, stream>>>(X, sc, out1);
    }
}